// Round 6
// baseline (272.191 us; speedup 1.0000x reference)
//
#include <hip/hip_runtime.h>

// Depthwise separable 4x4 FIR blur (StyleGAN2 upfirdn2d, up=down=1, pad=(2,2)).
// x: [B,C,256,256] f32, kernel: [4,4] f32 separable, out: [B,C,257,257] f32.
//
// out[q] = H[q+1] + v1*H[q] + v2*H[q-1] + v3*H[q-2],  H[r][c] = sum_j w[j]*x[r][c+1-j]
//
// R6: (1) 8-row groups: per wave visit, an 8KB contiguous read burst (8
// back-to-back 1KB wave loads) and an 8.2KB contiguous store burst — extends
// R5's 4KB-burst win (262->247us). (2) Grid = 1024 blocks, each handling 2
// ADJACENT planes (contiguous 512KB region/block); 1024 = 4 blocks/CU * 256
// exactly fills residency at <=128 VGPR — no ragged second round (occupancy
// was only ~75%). (3) unroll-2 ping-pong removes the G<-N register rotation.
// Halo via __shfl (cost-neutral vs extra loads, saves VMEM); regular stores
// (NT regressed in R4).

#define IW 256
#define IH 256
#define OW 257
#define OH 257

typedef float f4u __attribute__((vector_size(16), aligned(4)));

__device__ __forceinline__ float sbc(float v) {   // wave-uniform -> SGPR
    return __uint_as_float(__builtin_amdgcn_readfirstlane(__float_as_uint(v)));
}

__global__ __launch_bounds__(256, 4) void blur_fir_kernel(
    const float* __restrict__ x,
    const float* __restrict__ k2d,
    float* __restrict__ out)
{
    const int tid   = threadIdx.x;
    const int cg    = tid & 63;            // lane = column group: cols [4cg, 4cg+4)
    const int strip = tid >> 6;            // 0..3 (wave = 64-row strip)

    const float w0 = sbc(k2d[0]);
    const float w1 = sbc(k2d[1]);
    const float w2 = sbc(k2d[2]);
    const float w3 = sbc(k2d[3]);
    const float inv = 1.0f / w0;
    const float v1 = sbc(k2d[4]  * inv);
    const float v2 = sbc(k2d[8]  * inv);
    const float v3 = sbc(k2d[12] * inv);

    const int   c0 = cg << 2;
    const float mL = (cg > 0)  ? 1.0f : 0.0f;
    const float mR = (cg < 63) ? 1.0f : 0.0f;
    const int   lm = (cg > 0)  ? cg - 1 : 0;
    const int   lp = (cg < 63) ? cg + 1 : 63;
    const int   r0 = strip << 6;
    const bool last = (cg == 63);

    for (int pp = 0; pp < 2; ++pp) {
        const int plane = (blockIdx.x << 1) + pp;   // adjacent planes per block
        const float* xp = x + ((size_t)plane << 16);

        auto loadraw = [&](int r) -> float4 {
            int rr = min(max(r, 0), IH - 1);        // clamp; OOB masked in hcomb
            return *(const float4*)(xp + (rr << 8) + c0);
        };
        auto hcomb = [&](float4 Bv, int r, float4& h, float& h4) {
            float rm = (r >= 0 && r < IH) ? 1.0f : 0.0f;
            float lx = __shfl(Bv.z, lm, 64) * mL;   // x[r][c0-2]
            float ly = __shfl(Bv.w, lm, 64) * mL;   // x[r][c0-1]
            float rv = __shfl(Bv.x, lp, 64) * mR;   // x[r][c0+4]
            h.x = w0 * Bv.y + w1 * Bv.x + w2 * ly   + w3 * lx;
            h.y = w0 * Bv.z + w1 * Bv.y + w2 * Bv.x + w3 * ly;
            h.z = w0 * Bv.w + w1 * Bv.z + w2 * Bv.y + w3 * Bv.x;
            h.w = w0 * rv   + w1 * Bv.w + w2 * Bv.z + w3 * Bv.y;
            h4  = w2 * Bv.w + w3 * Bv.z;            // out col 256 (lane 63 only)
            h.x *= rm; h.y *= rm; h.z *= rm; h.w *= rm; h4 *= rm;
        };
        auto vcomb = [&](float4 a, float4 b, float4 c, float4 d) -> float4 {
            float4 r;
            r.x = a.x + v1 * b.x + v2 * c.x + v3 * d.x;
            r.y = a.y + v1 * b.y + v2 * c.y + v3 * d.y;
            r.z = a.z + v1 * b.z + v2 * c.z + v3 * d.z;
            r.w = a.w + v1 * b.w + v2 * c.w + v3 * d.w;
            return r;
        };

        // Prime carries C=H[r0-2..r0] and raw group G = rows r0+1..r0+8.
        float4 C0, C1, C2; float sc0, sc1, sc2;
        { float4 B = loadraw(r0 - 2); hcomb(B, r0 - 2, C0, sc0); }
        { float4 B = loadraw(r0 - 1); hcomb(B, r0 - 1, C1, sc1); }
        { float4 B = loadraw(r0    ); hcomb(B, r0    , C2, sc2); }
        float4 G0 = loadraw(r0 + 1), G1 = loadraw(r0 + 2);
        float4 G2 = loadraw(r0 + 3), G3 = loadraw(r0 + 4);
        float4 G4 = loadraw(r0 + 5), G5 = loadraw(r0 + 6);
        float4 G6 = loadraw(r0 + 7), G7 = loadraw(r0 + 8);

        float* op = out + (size_t)plane * (OW * OH) + (size_t)r0 * OW + c0;

        #pragma unroll 2
        for (int g = 0; g < 8; ++g) {
            const int rb = r0 + (g << 3);
            // prefetch next group's 8 rows: one 8KB contiguous wave burst
            float4 N0 = loadraw(rb + 9),  N1 = loadraw(rb + 10);
            float4 N2 = loadraw(rb + 11), N3 = loadraw(rb + 12);
            float4 N4 = loadraw(rb + 13), N5 = loadraw(rb + 14);
            float4 N6 = loadraw(rb + 15), N7 = loadraw(rb + 16);

            float4 F0, F1, F2, F3, F4, F5, F6, F7;
            float  sf0, sf1, sf2, sf3, sf4, sf5, sf6, sf7;
            hcomb(G0, rb + 1, F0, sf0);
            hcomb(G1, rb + 2, F1, sf1);
            hcomb(G2, rb + 3, F2, sf2);
            hcomb(G3, rb + 4, F3, sf3);
            hcomb(G4, rb + 5, F4, sf4);
            hcomb(G5, rb + 6, F5, sf5);
            hcomb(G6, rb + 7, F6, sf6);
            hcomb(G7, rb + 8, F7, sf7);

            float4 R0 = vcomb(F0, C2, C1, C0);
            float4 R1 = vcomb(F1, F0, C2, C1);
            float4 R2 = vcomb(F2, F1, F0, C2);
            float4 R3 = vcomb(F3, F2, F1, F0);
            float4 R4 = vcomb(F4, F3, F2, F1);
            float4 R5 = vcomb(F5, F4, F3, F2);
            float4 R6 = vcomb(F6, F5, F4, F3);
            float4 R7 = vcomb(F7, F6, F5, F4);
            *(f4u*)(op         ) = (f4u){R0.x, R0.y, R0.z, R0.w};
            *(f4u*)(op +     OW) = (f4u){R1.x, R1.y, R1.z, R1.w};
            *(f4u*)(op + 2 * OW) = (f4u){R2.x, R2.y, R2.z, R2.w};
            *(f4u*)(op + 3 * OW) = (f4u){R3.x, R3.y, R3.z, R3.w};
            *(f4u*)(op + 4 * OW) = (f4u){R4.x, R4.y, R4.z, R4.w};
            *(f4u*)(op + 5 * OW) = (f4u){R5.x, R5.y, R5.z, R5.w};
            *(f4u*)(op + 6 * OW) = (f4u){R6.x, R6.y, R6.z, R6.w};
            *(f4u*)(op + 7 * OW) = (f4u){R7.x, R7.y, R7.z, R7.w};
            if (last) {
                op[4]          = sf0 + v1 * sc2 + v2 * sc1 + v3 * sc0;
                op[OW + 4]     = sf1 + v1 * sf0 + v2 * sc2 + v3 * sc1;
                op[2 * OW + 4] = sf2 + v1 * sf1 + v2 * sf0 + v3 * sc2;
                op[3 * OW + 4] = sf3 + v1 * sf2 + v2 * sf1 + v3 * sf0;
                op[4 * OW + 4] = sf4 + v1 * sf3 + v2 * sf2 + v3 * sf1;
                op[5 * OW + 4] = sf5 + v1 * sf4 + v2 * sf3 + v3 * sf2;
                op[6 * OW + 4] = sf6 + v1 * sf5 + v2 * sf4 + v3 * sf3;
                op[7 * OW + 4] = sf7 + v1 * sf6 + v2 * sf5 + v3 * sf4;
            }
            op += 8 * OW;

            C0 = F5;  C1 = F6;  C2 = F7;
            sc0 = sf5; sc1 = sf6; sc2 = sf7;
            G0 = N0; G1 = N1; G2 = N2; G3 = N3;
            G4 = N4; G5 = N5; G6 = N6; G7 = N7;
        }

        if (strip == 3) {                  // out row 256: H[257]=0, C2=H[256]=0
            float4 R;
            R.x = v1 * C2.x + v2 * C1.x + v3 * C0.x;
            R.y = v1 * C2.y + v2 * C1.y + v3 * C0.y;
            R.z = v1 * C2.z + v2 * C1.z + v3 * C0.z;
            R.w = v1 * C2.w + v2 * C1.w + v3 * C0.w;
            *(f4u*)op = (f4u){R.x, R.y, R.z, R.w};
            if (last) op[4] = v1 * sc2 + v2 * sc1 + v3 * sc0;
        }
    }
}

extern "C" void kernel_launch(void* const* d_in, const int* in_sizes, int n_in,
                              void* d_out, int out_size, void* d_ws, size_t ws_size,
                              hipStream_t stream) {
    const float* x   = (const float*)d_in[0];
    const float* k2d = (const float*)d_in[1];
    float* out = (float*)d_out;

    int nplanes = in_sizes[0] >> 16;       // B*C = 2048
    int nblocks = nplanes >> 1;            // 1024 blocks x 2 adjacent planes
    blur_fir_kernel<<<nblocks, 256, 0, stream>>>(x, k2d, out);
}

// Round 7
// 243.058 us; speedup vs baseline: 1.1199x; 1.1199x over previous
//
#include <hip/hip_runtime.h>

// Depthwise separable 4x4 FIR blur (StyleGAN2 upfirdn2d, up=down=1, pad=(2,2)).
// x: [B,C,256,256] f32, kernel: [4,4] f32 separable, out: [B,C,257,257] f32.
//
// out[q] = H[q+1] + v1*H[q] + v2*H[q-1] + v3*H[q-2],  H[r][c] = sum_j w[j]*x[r][c+1-j]
//
// R7: identical inner structure to R5 (best: 247us — 4-row groups, depth-1
// group prefetch, shfl halo, plain stores), repackaged for RESIDENCY:
// 128-thread blocks (2 waves), 4096 blocks. Exact-fit 256-thread grids showed
// OccupancyPercent stuck at 67-75% in every round (one-shot ration, no
// backfill; kernel ends at the slowest CU's pace) — that ~25% idle is roughly
// the whole remaining gap to the mixed-R/W HBM floor. Oversubscribed 2-wave
// blocks let the command processor backfill CUs continuously.
// No __launch_bounds__ min-wave cap (R6's 128-VGPR cap caused the regression).

#define IW 256
#define IH 256
#define OW 257
#define OH 257

typedef float f4u __attribute__((vector_size(16), aligned(4)));

__device__ __forceinline__ float sbc(float v) {   // wave-uniform -> SGPR
    return __uint_as_float(__builtin_amdgcn_readfirstlane(__float_as_uint(v)));
}

__global__ __launch_bounds__(128) void blur_fir_kernel(
    const float* __restrict__ x,
    const float* __restrict__ k2d,
    float* __restrict__ out)
{
    const int tid   = threadIdx.x;
    const int cg    = tid & 63;                 // lane = column group: cols [4cg,4cg+4)
    const int wv    = tid >> 6;                 // 0..1
    const int strip = ((blockIdx.x & 1) << 1) + wv;   // 0..3 (64-row strip)
    const int plane = blockIdx.x >> 1;

    const float w0 = sbc(k2d[0]);
    const float w1 = sbc(k2d[1]);
    const float w2 = sbc(k2d[2]);
    const float w3 = sbc(k2d[3]);
    const float inv = 1.0f / w0;
    const float v1 = sbc(k2d[4]  * inv);
    const float v2 = sbc(k2d[8]  * inv);
    const float v3 = sbc(k2d[12] * inv);

    const int   c0 = cg << 2;
    const float mL = (cg > 0)  ? 1.0f : 0.0f;
    const float mR = (cg < 63) ? 1.0f : 0.0f;
    const int   lm = (cg > 0)  ? cg - 1 : 0;    // neighbor-left lane
    const int   lp = (cg < 63) ? cg + 1 : 63;   // neighbor-right lane

    const float* xp = x + ((size_t)plane << 16);
    const int r0 = strip << 6;

    auto loadraw = [&](int r) -> float4 {
        int rr = min(max(r, 0), IH - 1);        // clamp; OOB rows masked in hcomb
        return *(const float4*)(xp + (rr << 8) + c0);
    };
    auto hcomb = [&](float4 Bv, int r, float4& h, float& h4) {
        float rm = (r >= 0 && r < IH) ? 1.0f : 0.0f;
        float lx = __shfl(Bv.z, lm, 64) * mL;   // x[r][c0-2]
        float ly = __shfl(Bv.w, lm, 64) * mL;   // x[r][c0-1]
        float rv = __shfl(Bv.x, lp, 64) * mR;   // x[r][c0+4]
        h.x = w0 * Bv.y + w1 * Bv.x + w2 * ly   + w3 * lx;
        h.y = w0 * Bv.z + w1 * Bv.y + w2 * Bv.x + w3 * ly;
        h.z = w0 * Bv.w + w1 * Bv.z + w2 * Bv.y + w3 * Bv.x;
        h.w = w0 * rv   + w1 * Bv.w + w2 * Bv.z + w3 * Bv.y;
        h4  = w2 * Bv.w + w3 * Bv.z;            // out col 256 (lane 63 only)
        h.x *= rm; h.y *= rm; h.z *= rm; h.w *= rm; h4 *= rm;
    };
    auto vcomb = [&](float4 a, float4 b, float4 c, float4 d) -> float4 {
        float4 r;
        r.x = a.x + v1 * b.x + v2 * c.x + v3 * d.x;
        r.y = a.y + v1 * b.y + v2 * c.y + v3 * d.y;
        r.z = a.z + v1 * b.z + v2 * c.z + v3 * d.z;
        r.w = a.w + v1 * b.w + v2 * c.w + v3 * d.w;
        return r;
    };

    // Carry ring: C0=H[rb-2], C1=H[rb-1], C2=H[rb]  (+ col-256 scalars)
    float4 C0, C1, C2; float sc0, sc1, sc2;
    { float4 B = loadraw(r0 - 2); hcomb(B, r0 - 2, C0, sc0); }
    { float4 B = loadraw(r0 - 1); hcomb(B, r0 - 1, C1, sc1); }
    { float4 B = loadraw(r0    ); hcomb(B, r0    , C2, sc2); }

    // Current raw group: input rows rb+1..rb+4 (4KB contiguous per wave)
    float4 G0 = loadraw(r0 + 1);
    float4 G1 = loadraw(r0 + 2);
    float4 G2 = loadraw(r0 + 3);
    float4 G3 = loadraw(r0 + 4);

    float* op = out + (size_t)plane * (OW * OH) + (size_t)r0 * OW + c0;
    const bool last = (cg == 63);

    #pragma unroll 2
    for (int g = 0; g < 16; ++g) {
        const int rb = r0 + (g << 2);
        // prefetch next group's rows (4KB contiguous burst), consumed next iter
        float4 N0 = loadraw(rb + 5);
        float4 N1 = loadraw(rb + 6);
        float4 N2 = loadraw(rb + 7);
        float4 N3 = loadraw(rb + 8);

        float4 F0, F1, F2, F3; float sf0, sf1, sf2, sf3;
        hcomb(G0, rb + 1, F0, sf0);
        hcomb(G1, rb + 2, F1, sf1);
        hcomb(G2, rb + 3, F2, sf2);
        hcomb(G3, rb + 4, F3, sf3);

        float4 R0 = vcomb(F0, C2, C1, C0);      // out row rb
        float4 R1 = vcomb(F1, F0, C2, C1);      // out row rb+1
        float4 R2 = vcomb(F2, F1, F0, C2);      // out row rb+2
        float4 R3 = vcomb(F3, F2, F1, F0);      // out row rb+3
        *(f4u*)(op         ) = (f4u){R0.x, R0.y, R0.z, R0.w};
        *(f4u*)(op +     OW) = (f4u){R1.x, R1.y, R1.z, R1.w};
        *(f4u*)(op + 2 * OW) = (f4u){R2.x, R2.y, R2.z, R2.w};
        *(f4u*)(op + 3 * OW) = (f4u){R3.x, R3.y, R3.z, R3.w};
        if (last) {
            op[4]          = sf0 + v1 * sc2 + v2 * sc1 + v3 * sc0;
            op[OW + 4]     = sf1 + v1 * sf0 + v2 * sc2 + v3 * sc1;
            op[2 * OW + 4] = sf2 + v1 * sf1 + v2 * sf0 + v3 * sc2;
            op[3 * OW + 4] = sf3 + v1 * sf2 + v2 * sf1 + v3 * sf0;
        }
        op += 4 * OW;

        C0 = F1;  C1 = F2;  C2 = F3;
        sc0 = sf1; sc1 = sf2; sc2 = sf3;
        G0 = N0; G1 = N1; G2 = N2; G3 = N3;
    }

    if (strip == 3) {                           // out row 256 (H[257] == 0)
        float4 R;
        R.x = v1 * C2.x + v2 * C1.x + v3 * C0.x;
        R.y = v1 * C2.y + v2 * C1.y + v3 * C0.y;
        R.z = v1 * C2.z + v2 * C1.z + v3 * C0.z;
        R.w = v1 * C2.w + v2 * C1.w + v3 * C0.w;
        *(f4u*)op = (f4u){R.x, R.y, R.z, R.w};
        if (last) op[4] = v1 * sc2 + v2 * sc1 + v3 * sc0;
    }
}

extern "C" void kernel_launch(void* const* d_in, const int* in_sizes, int n_in,
                              void* d_out, int out_size, void* d_ws, size_t ws_size,
                              hipStream_t stream) {
    const float* x   = (const float*)d_in[0];
    const float* k2d = (const float*)d_in[1];
    float* out = (float*)d_out;

    int nplanes = in_sizes[0] >> 16;            // B*C = 2048
    int nblocks = nplanes * 2;                  // 2 strips per 128-thread block
    blur_fir_kernel<<<nblocks, 128, 0, stream>>>(x, k2d, out);
}

// Round 8
// 234.592 us; speedup vs baseline: 1.1603x; 1.0361x over previous
//
#include <hip/hip_runtime.h>

// Depthwise separable 4x4 FIR blur (StyleGAN2 upfirdn2d, up=down=1, pad=(2,2)).
// x: [B,C,256,256] f32, kernel: [4,4] f32 separable, out: [B,C,257,257] f32.
//
// out[q] = H[q+1] + v1*H[q] + v2*H[q-1] + v3*H[q-2],  H[r][c] = sum_j w[j]*x[r][c+1-j]
//
// R8: GLOBAL SWEEP. R2-R7 exhausted per-wave structure (burst size, prefetch
// depth, occupancy, residency) — all plateau at ~245-265us / 3.5 TB/s with no
// pipe saturated. Every variant shared one property: 8192 private strip
// streams = a scattered ~250MB instantaneous window. The kernels that DO hit
// 6.3-6.8 TB/s (fillBuffer, float4 copy) sweep ONE compact contiguous window.
// Here: task = 4-output-row group; task id strides by total wave count, so all
// waves collectively process ~8192 consecutive groups (~33MB sweeping window).
// Groups are self-contained (load 7 input rows, compute 7 H, 4 outputs); the
// 1.75x L1-level read amplification is absorbed by warm L2/L3 (neighboring
// tasks overlap 3 rows and run simultaneously). No carry ring, no reg
// prefetch -> ~60 VGPR -> 8 waves/SIMD.

#define IW 256
#define IH 256
#define OW 257
#define OH 257
#define NG 65            // row-group tasks per plane: 64 full (4 rows) + 1 (row 256)

typedef float f4u __attribute__((vector_size(16), aligned(4)));

__device__ __forceinline__ float sbc(float v) {   // wave-uniform -> SGPR
    return __uint_as_float(__builtin_amdgcn_readfirstlane(__float_as_uint(v)));
}

__global__ __launch_bounds__(256) void blur_fir_kernel(
    const float* __restrict__ x,
    const float* __restrict__ k2d,
    float* __restrict__ out,
    int ntasks, int nwaves)
{
    const int lane = threadIdx.x & 63;
    const int gw   = (blockIdx.x << 2) + (threadIdx.x >> 6);   // global wave id

    const float w0 = sbc(k2d[0]);
    const float w1 = sbc(k2d[1]);
    const float w2 = sbc(k2d[2]);
    const float w3 = sbc(k2d[3]);
    const float inv = 1.0f / w0;
    const float v1 = sbc(k2d[4]  * inv);
    const float v2 = sbc(k2d[8]  * inv);
    const float v3 = sbc(k2d[12] * inv);

    const int   c0 = lane << 2;
    const float mL = (lane > 0)  ? 1.0f : 0.0f;
    const float mR = (lane < 63) ? 1.0f : 0.0f;
    const int   lm = (lane > 0)  ? lane - 1 : 0;
    const int   lp = (lane < 63) ? lane + 1 : 63;
    const bool last = (lane == 63);

    for (int t = gw; t < ntasks; t += nwaves) {
        const int plane = t / NG;                  // const div -> magic mul
        const int rg    = t - plane * NG;
        const float* xp = x + ((size_t)plane << 16);
        float* op = out + (size_t)plane * (OW * OH) + (size_t)(rg << 2) * OW + c0;

        auto loadraw = [&](int r) -> float4 {
            int rr = min(max(r, 0), IH - 1);       // clamp; OOB masked in hcomb
            return *(const float4*)(xp + (rr << 8) + c0);
        };
        auto hcomb = [&](float4 Bv, int r, float4& h, float& h4) {
            float rm = (r >= 0 && r < IH) ? 1.0f : 0.0f;
            float lx = __shfl(Bv.z, lm, 64) * mL;  // x[r][c0-2]
            float ly = __shfl(Bv.w, lm, 64) * mL;  // x[r][c0-1]
            float rv = __shfl(Bv.x, lp, 64) * mR;  // x[r][c0+4]
            h.x = w0 * Bv.y + w1 * Bv.x + w2 * ly   + w3 * lx;
            h.y = w0 * Bv.z + w1 * Bv.y + w2 * Bv.x + w3 * ly;
            h.z = w0 * Bv.w + w1 * Bv.z + w2 * Bv.y + w3 * Bv.x;
            h.w = w0 * rv   + w1 * Bv.w + w2 * Bv.z + w3 * Bv.y;
            h4  = w2 * Bv.w + w3 * Bv.z;           // out col 256 (lane 63 only)
            h.x *= rm; h.y *= rm; h.z *= rm; h.w *= rm; h4 *= rm;
        };
        auto vcomb = [&](float4 a, float4 b, float4 c, float4 d) -> float4 {
            float4 r;
            r.x = a.x + v1 * b.x + v2 * c.x + v3 * d.x;
            r.y = a.y + v1 * b.y + v2 * c.y + v3 * d.y;
            r.z = a.z + v1 * b.z + v2 * c.z + v3 * d.z;
            r.w = a.w + v1 * b.w + v2 * c.w + v3 * d.w;
            return r;
        };

        if (rg < 64) {
            const int rb = rg << 2;                // out rows rb..rb+3
            // 7 input rows rb-2..rb+4, all independent loads (one latency/iter)
            float4 G0 = loadraw(rb - 2), G1 = loadraw(rb - 1), G2 = loadraw(rb);
            float4 G3 = loadraw(rb + 1), G4 = loadraw(rb + 2), G5 = loadraw(rb + 3);
            float4 G6 = loadraw(rb + 4);

            float4 F0, F1, F2, F3, F4, F5, F6;
            float  s0, s1, s2, s3, s4, s5, s6;
            hcomb(G0, rb - 2, F0, s0);
            hcomb(G1, rb - 1, F1, s1);
            hcomb(G2, rb    , F2, s2);
            hcomb(G3, rb + 1, F3, s3);
            hcomb(G4, rb + 2, F4, s4);
            hcomb(G5, rb + 3, F5, s5);
            hcomb(G6, rb + 4, F6, s6);

            float4 R0 = vcomb(F3, F2, F1, F0);     // out row rb
            float4 R1 = vcomb(F4, F3, F2, F1);     // out row rb+1
            float4 R2 = vcomb(F5, F4, F3, F2);     // out row rb+2
            float4 R3 = vcomb(F6, F5, F4, F3);     // out row rb+3
            *(f4u*)(op         ) = (f4u){R0.x, R0.y, R0.z, R0.w};
            *(f4u*)(op +     OW) = (f4u){R1.x, R1.y, R1.z, R1.w};
            *(f4u*)(op + 2 * OW) = (f4u){R2.x, R2.y, R2.z, R2.w};
            *(f4u*)(op + 3 * OW) = (f4u){R3.x, R3.y, R3.z, R3.w};
            if (last) {
                op[4]          = s3 + v1 * s2 + v2 * s1 + v3 * s0;
                op[OW + 4]     = s4 + v1 * s3 + v2 * s2 + v3 * s1;
                op[2 * OW + 4] = s5 + v1 * s4 + v2 * s3 + v3 * s2;
                op[3 * OW + 4] = s6 + v1 * s5 + v2 * s4 + v3 * s3;
            }
        } else {
            // out row 256: H[256]=H[257]=0 -> v2*H[255] + v3*H[254]
            float4 GA = loadraw(254), GB = loadraw(255);
            float4 FA, FB; float sA, sB;
            hcomb(GA, 254, FA, sA);
            hcomb(GB, 255, FB, sB);
            float4 R;
            R.x = v2 * FB.x + v3 * FA.x;
            R.y = v2 * FB.y + v3 * FA.y;
            R.z = v2 * FB.z + v3 * FA.z;
            R.w = v2 * FB.w + v3 * FA.w;
            *(f4u*)op = (f4u){R.x, R.y, R.z, R.w};
            if (last) op[4] = v2 * sB + v3 * sA;
        }
    }
}

extern "C" void kernel_launch(void* const* d_in, const int* in_sizes, int n_in,
                              void* d_out, int out_size, void* d_ws, size_t ws_size,
                              hipStream_t stream) {
    const float* x   = (const float*)d_in[0];
    const float* k2d = (const float*)d_in[1];
    float* out = (float*)d_out;

    int nplanes = in_sizes[0] >> 16;               // B*C = 2048
    int ntasks  = nplanes * NG;                    // 133120 group tasks
    int nblocks = 2048;                            // 8192 waves total
    int nwaves  = nblocks * 4;

    blur_fir_kernel<<<nblocks, 256, 0, stream>>>(x, k2d, out, ntasks, nwaves);
}